// Round 3
// baseline (261.943 us; speedup 1.0000x reference)
//
#include <hip/hip_runtime.h>
#include <hip/hip_bf16.h>

// ECE over logits (8,19,512,1024) f32, labels (8,512,1024) int32.
// confidence = 1/sum(exp(l - lmax)); prediction = argmax (first-max, matches jnp).
// bin = clip(ceil(conf*15)-1, 0, 14).
// R3: revert NT loads + unroll-1 (R2 regression: latency-bound at 48 VGPR).
//     2 pixel-groups per thread, all 40 vector loads issued before consumption (MLP).
//     64-replica LDS bins: slot = bin*64 + lane -> no intra-wave same-address
//     serialization, bank = lane%32 (conflict-free). cnt|corr merged in one u32.
//     Fused last-block finalize (device-scope done counter).

constexpr int NBINS = 15;
constexpr int NC    = 19;      // classes (fixed by reference)
constexpr int HWSH  = 19;      // H*W = 512*1024 = 2^19 (fixed by reference)

typedef float f32x4 __attribute__((ext_vector_type(4)));
typedef int   i32x4 __attribute__((ext_vector_type(4)));

__global__ __launch_bounds__(256) void ece_fused_kernel(
    const float* __restrict__ logits,
    const int*   __restrict__ labels,
    double*       __restrict__ g_conf,   // [NBINS]
    unsigned int* __restrict__ g_cnt,    // [NBINS]
    unsigned int* __restrict__ g_corr,   // [NBINS]
    unsigned int* __restrict__ g_done,   // [1]
    float*        __restrict__ out,
    int P4)                              // number of 4-pixel groups
{
    __shared__ unsigned s_mc[NBINS * 64];   // (cnt<<16)|corr per (bin, lane-replica)
    __shared__ float    s_cf[NBINS * 64];   // conf sum per (bin, lane-replica)
    __shared__ unsigned s_last;

    const int t = threadIdx.x;
    for (int i = t; i < NBINS * 64; i += 256) { s_mc[i] = 0u; s_cf[i] = 0.0f; }
    if (t == 0) s_last = 0;
    __syncthreads();

    const int lane = t & 63;
    const int HW   = 1 << HWSH;
    const int T    = gridDim.x * 256;    // total threads

    for (int g0 = blockIdx.x * 256 + t; g0 < P4; g0 += 2 * T) {
        const int  g1   = g0 + T;
        const bool has1 = (g1 < P4);

        // ---- issue ALL loads first (MLP: up to 40 dwordx4 in flight) ----
        const int p0 = g0 << 2;
        const float* b0 = logits + (((size_t)((p0 >> HWSH) * NC)) << HWSH) + (p0 & (HW - 1));
        f32x4 v0[NC];
        #pragma unroll
        for (int c = 0; c < NC; ++c)
            v0[c] = *reinterpret_cast<const f32x4*>(b0 + ((size_t)c << HWSH));
        const i32x4 lab0 = *reinterpret_cast<const i32x4*>(labels + p0);

        const int p1 = has1 ? (g1 << 2) : p0;
        const float* b1 = logits + (((size_t)((p1 >> HWSH) * NC)) << HWSH) + (p1 & (HW - 1));
        f32x4 v1[NC];
        #pragma unroll
        for (int c = 0; c < NC; ++c)
            v1[c] = *reinterpret_cast<const f32x4*>(b1 + ((size_t)c << HWSH));
        const i32x4 lab1 = *reinterpret_cast<const i32x4*>(labels + p1);

        // ---- consume group 0 ----
        #pragma unroll
        for (int j = 0; j < 4; ++j) {
            float mx = v0[0][j];
            int   am = 0;
            #pragma unroll
            for (int c = 1; c < NC; ++c)
                if (v0[c][j] > mx) { mx = v0[c][j]; am = c; }   // strict > = first max
            float s = 0.0f;
            #pragma unroll
            for (int c = 0; c < NC; ++c) s += __expf(v0[c][j] - mx);
            const float conf = 1.0f / s;
            int b = (int)ceilf(conf * 15.0f) - 1;
            b = b < 0 ? 0 : (b > NBINS - 1 ? NBINS - 1 : b);
            const int idx = b * 64 + lane;
            atomicAdd(&s_mc[idx], 0x10000u | (unsigned)(am == lab0[j]));
            atomicAdd(&s_cf[idx], conf);
        }
        // ---- consume group 1 ----
        if (has1) {
            #pragma unroll
            for (int j = 0; j < 4; ++j) {
                float mx = v1[0][j];
                int   am = 0;
                #pragma unroll
                for (int c = 1; c < NC; ++c)
                    if (v1[c][j] > mx) { mx = v1[c][j]; am = c; }
                float s = 0.0f;
                #pragma unroll
                for (int c = 0; c < NC; ++c) s += __expf(v1[c][j] - mx);
                const float conf = 1.0f / s;
                int b = (int)ceilf(conf * 15.0f) - 1;
                b = b < 0 ? 0 : (b > NBINS - 1 ? NBINS - 1 : b);
                const int idx = b * 64 + lane;
                atomicAdd(&s_mc[idx], 0x10000u | (unsigned)(am == lab1[j]));
                atomicAdd(&s_cf[idx], conf);
            }
        }
    }
    __syncthreads();

    // Block reduction -> device-scope global atomics.
    // Per-block cnt per bin <= 2048 pixels -> (cnt<<16) fits u32, corr never carries.
    if (t < NBINS) {
        unsigned mc = 0u;
        float    cf = 0.0f;
        #pragma unroll 4
        for (int r = 0; r < 64; ++r) { mc += s_mc[t * 64 + r]; cf += s_cf[t * 64 + r]; }
        if (mc) {
            atomicAdd(&g_cnt [t], mc >> 16);
            atomicAdd(&g_corr[t], mc & 0xFFFFu);
            atomicAdd(&g_conf[t], (double)cf);
        }
    }
    __syncthreads();   // all global atomics issued before done-count

    if (t == 0) {
        __threadfence();  // release: this block's sums visible device-wide
        const unsigned prev = __hip_atomic_fetch_add(
            g_done, 1u, __ATOMIC_ACQ_REL, __HIP_MEMORY_SCOPE_AGENT);
        if (prev == gridDim.x - 1) s_last = 1;
    }
    __syncthreads();

    if (s_last && t == 0) {
        const double total = (double)P4 * 4.0;
        double e = 0.0;
        for (int b = 0; b < NBINS; ++b) {
            const unsigned cnt = __hip_atomic_load(&g_cnt[b],  __ATOMIC_RELAXED, __HIP_MEMORY_SCOPE_AGENT);
            const unsigned cor = __hip_atomic_load(&g_corr[b], __ATOMIC_RELAXED, __HIP_MEMORY_SCOPE_AGENT);
            const double   cf  = __hip_atomic_load(&g_conf[b], __ATOMIC_RELAXED, __HIP_MEMORY_SCOPE_AGENT);
            if (cnt) {
                const double c = (double)cnt;
                e += fabs(cf / c - (double)cor / c) * (c / total);
            }
        }
        out[0] = (float)e;
    }
}

extern "C" void kernel_launch(void* const* d_in, const int* in_sizes, int n_in,
                              void* d_out, int out_size, void* d_ws, size_t ws_size,
                              hipStream_t stream) {
    const float* logits = (const float*)d_in[0];
    const int*   labels = (const int*)d_in[1];   // harness converts integer inputs to int32
    float*       out    = (float*)d_out;

    const int P  = in_sizes[1];   // 8*512*1024 = 4,194,304 pixels
    const int P4 = P >> 2;

    // Workspace: [0..120) double conf[15]; [128..188) uint cnt[15];
    //            [192..252) uint corr[15]; [252..256) uint done
    double*       g_conf = (double*)d_ws;
    unsigned int* g_cnt  = (unsigned int*)((char*)d_ws + 128);
    unsigned int* g_corr = (unsigned int*)((char*)d_ws + 192);
    unsigned int* g_done = (unsigned int*)((char*)d_ws + 252);

    hipMemsetAsync(d_ws, 0, 256, stream);  // deterministic re-zero every call

    int blocks = (P4 + 511) / 512;         // 2 groups per thread
    if (blocks > 2048) blocks = 2048;
    ece_fused_kernel<<<blocks, 256, 0, stream>>>(
        logits, labels, g_conf, g_cnt, g_corr, g_done, out, P4);
}

// Round 4
// 91.233 us; speedup vs baseline: 2.8711x; 2.8711x over previous
//
#include <hip/hip_runtime.h>
#include <hip/hip_bf16.h>

// ECE over logits (8,19,512,1024) f32, labels (8,512,1024) int32.
// R4: back to R1's 3-dispatch structure (no fences / done-counter — R2/R3's fused
//     tail + two-pass register dataflow caused a 3x regression that was HBM-independent).
//     Online softmax-max: single pass over classes, each value consumed once ->
//     low VGPR without reloads; loads stream ahead of 4 independent compute chains.
//     conf = 1/s with s = sum exp(v - m) maintained online (flash-attention style).
//     64-replica LDS bins: slot = bin*64+lane (intra-wave conflict-free), cnt|corr
//     merged into one u32 -> 2 LDS atomics/pixel.

constexpr int NBINS = 15;
constexpr int NC    = 19;      // classes (fixed by reference)
constexpr int HWSH  = 19;      // H*W = 512*1024 = 2^19 (fixed by reference)

typedef float f32x4 __attribute__((ext_vector_type(4)));
typedef int   i32x4 __attribute__((ext_vector_type(4)));

__global__ __launch_bounds__(256) void ece_partial_kernel(
    const float* __restrict__ logits,
    const int*   __restrict__ labels,
    double*       __restrict__ g_conf,   // [NBINS]
    unsigned int* __restrict__ g_cnt,    // [NBINS]
    unsigned int* __restrict__ g_corr,   // [NBINS]
    int P4)                              // number of 4-pixel groups
{
    __shared__ unsigned s_mc[NBINS * 64];   // (cnt<<16)|corr per (bin, lane-replica)
    __shared__ float    s_cf[NBINS * 64];   // conf sum per (bin, lane-replica)

    const int t = threadIdx.x;
    for (int i = t; i < NBINS * 64; i += 256) { s_mc[i] = 0u; s_cf[i] = 0.0f; }
    __syncthreads();

    const int lane   = t & 63;
    const int HW     = 1 << HWSH;
    const int stride = gridDim.x * 256;

    for (int g = blockIdx.x * 256 + t; g < P4; g += stride) {
        const int p   = g << 2;              // first pixel of this 4-group
        const int n   = p >> HWSH;           // image index
        const int rem = p & (HW - 1);        // h*W + w within the image
        const float* base = logits + (((size_t)(n * NC)) << HWSH) + rem;

        const i32x4 lab = *reinterpret_cast<const i32x4*>(labels + p);  // in flight early

        // ---- online softmax-max over 19 classes, 4 pixels in parallel ----
        // state per pixel j: m = running max, s = sum exp(v - m), am = first argmax
        f32x4 x = *reinterpret_cast<const f32x4*>(base);
        float m[4]  = { x[0], x[1], x[2], x[3] };
        float s[4]  = { 1.0f, 1.0f, 1.0f, 1.0f };
        int   am[4] = { 0, 0, 0, 0 };

        #pragma unroll
        for (int c = 1; c < NC; ++c) {
            const f32x4 v = *reinterpret_cast<const f32x4*>(base + ((size_t)c << HWSH));
            #pragma unroll
            for (int j = 0; j < 4; ++j) {
                const float vj = v[j];
                const bool  gt = vj > m[j];                 // strict > keeps first max
                const float e  = __expf(-fabsf(vj - m[j])); // exp(m-v) or exp(v-m)
                s[j]  = gt ? s[j] * e + 1.0f : s[j] + e;
                am[j] = gt ? c : am[j];
                m[j]  = gt ? vj : m[j];
            }
        }

        #pragma unroll
        for (int j = 0; j < 4; ++j) {
            const float conf = 1.0f / s[j];
            int b = (int)ceilf(conf * 15.0f) - 1;           // (lo,hi] bins
            b = b < 0 ? 0 : (b > NBINS - 1 ? NBINS - 1 : b);
            const int idx = b * 64 + lane;
            atomicAdd(&s_mc[idx], 0x10000u | (unsigned)(am[j] == lab[j]));
            atomicAdd(&s_cf[idx], conf);
        }
    }
    __syncthreads();

    // Block reduction -> plain (relaxed) device atomics. Per-block cnt/bin <= 2048
    // pixels so (cnt<<16) never overflows and corr never carries into cnt.
    if (t < NBINS) {
        unsigned mc = 0u;
        float    cf = 0.0f;
        #pragma unroll 4
        for (int r = 0; r < 64; ++r) { mc += s_mc[t * 64 + r]; cf += s_cf[t * 64 + r]; }
        if (mc) {
            atomicAdd(&g_cnt [t], mc >> 16);
            atomicAdd(&g_corr[t], mc & 0xFFFFu);
            atomicAdd(&g_conf[t], (double)cf);
        }
    }
}

__global__ void ece_final_kernel(const double* __restrict__ g_conf,
                                 const unsigned int* __restrict__ g_cnt,
                                 const unsigned int* __restrict__ g_corr,
                                 float* __restrict__ out, float total)
{
    if (threadIdx.x == 0 && blockIdx.x == 0) {
        double e = 0.0;
        for (int b = 0; b < NBINS; ++b) {
            const double c = (double)g_cnt[b];
            if (c > 0.0) {
                const double acc = (double)g_corr[b] / c;
                const double avg = g_conf[b] / c;
                e += fabs(avg - acc) * (c / (double)total);
            }
        }
        out[0] = (float)e;
    }
}

extern "C" void kernel_launch(void* const* d_in, const int* in_sizes, int n_in,
                              void* d_out, int out_size, void* d_ws, size_t ws_size,
                              hipStream_t stream) {
    const float* logits = (const float*)d_in[0];
    const int*   labels = (const int*)d_in[1];   // harness converts integer inputs to int32
    float*       out    = (float*)d_out;

    const int P  = in_sizes[1];   // 8*512*1024 = 4,194,304 pixels
    const int P4 = P >> 2;

    // Workspace: [0..120) double conf[15]; [128..188) uint cnt[15]; [192..252) uint corr[15]
    double*       g_conf = (double*)d_ws;
    unsigned int* g_cnt  = (unsigned int*)((char*)d_ws + 128);
    unsigned int* g_corr = (unsigned int*)((char*)d_ws + 192);

    hipMemsetAsync(d_ws, 0, 256, stream);  // deterministic re-zero every call

    int blocks = (P4 + 255) / 256;
    if (blocks > 2048) blocks = 2048;
    ece_partial_kernel<<<blocks, 256, 0, stream>>>(logits, labels, g_conf, g_cnt, g_corr, P4);
    ece_final_kernel<<<1, 64, 0, stream>>>(g_conf, g_cnt, g_corr, out, (float)P);
}